// Round 22
// baseline (103.013 us; speedup 1.0000x reference)
//
#include <hip/hip_runtime.h>

#define NN 50000
#define NE 640000
#define CH 128
#define CAP 64                          // slots per node; P(deg>=64)~e^-61 for Poisson(12.8)
#define G1B ((NN + 63) / 64)            // 782 gemm1 blocks
#define FILLB ((NE + 255) / 256)        // 2500 fill blocks (un-partitioned)
#define XPAD 136                        // LDS x-tile pitch (ushorts)
#define CSTR 16                         // cnt stride in ints: 1 counter per 64B line
#define ZB ((NN * CSTR / 4 + 255) / 256)  // zero blocks (uint4)

typedef __attribute__((ext_vector_type(8))) short bf16x8;
typedef __attribute__((ext_vector_type(4))) float f32x4;
typedef __attribute__((ext_vector_type(2))) float f32x2;

#if __has_builtin(__builtin_amdgcn_cvt_pk_f32_fp8) && __has_builtin(__builtin_amdgcn_cvt_pk_fp8_f32)
#define HWFP8 1
#else
#define HWFP8 0
#endif

// f32 -> bf16 (RNE)
__device__ __forceinline__ unsigned short f2bf(float x) {
    unsigned int b = __float_as_uint(x);
    b += 0x7fffu + ((b >> 16) & 1u);
    return (unsigned short)(b >> 16);
}

// ---- fp8 e4m3 manual fallback codecs ----
__device__ __forceinline__ float fp8dec_sw(unsigned int b) {
    unsigned int m = (b & 0x7fu) << 20;
    unsigned int v = m ? (m + 0x3C000000u) : 0u;
    v |= (b & 0x80u) << 24;
    return __uint_as_float(v);
}
__device__ __forceinline__ unsigned int fp8enc_sw(float x) {
    unsigned int u = __float_as_uint(x);
    unsigned int s = (u >> 24) & 0x80u;
    u &= 0x7fffffffu;
    if (u > 0x43E00000u) u = 0x43E00000u;
    unsigned int r = u + 0x7FFFFu + ((u >> 20) & 1u);
    int b = (int)(r >> 20) - 960;
    b = b < 0 ? 0 : (b > 126 ? 126 : b);
    return s | (unsigned int)b;
}

// accumulate one fp8 row-chunk (8 channels in uint2) with mask m
__device__ __forceinline__ void acc_fp8(float* acc, uint2 v, float m) {
#if HWFP8
    f32x2 p0 = __builtin_amdgcn_cvt_pk_f32_fp8((int)v.x, false);
    f32x2 p1 = __builtin_amdgcn_cvt_pk_f32_fp8((int)v.x, true);
    f32x2 p2 = __builtin_amdgcn_cvt_pk_f32_fp8((int)v.y, false);
    f32x2 p3 = __builtin_amdgcn_cvt_pk_f32_fp8((int)v.y, true);
    acc[0] = fmaf(m, p0[0], acc[0]); acc[1] = fmaf(m, p0[1], acc[1]);
    acc[2] = fmaf(m, p1[0], acc[2]); acc[3] = fmaf(m, p1[1], acc[3]);
    acc[4] = fmaf(m, p2[0], acc[4]); acc[5] = fmaf(m, p2[1], acc[5]);
    acc[6] = fmaf(m, p3[0], acc[6]); acc[7] = fmaf(m, p3[1], acc[7]);
#else
    acc[0] = fmaf(m, fp8dec_sw(v.x & 0xffu), acc[0]);
    acc[1] = fmaf(m, fp8dec_sw((v.x >> 8) & 0xffu), acc[1]);
    acc[2] = fmaf(m, fp8dec_sw((v.x >> 16) & 0xffu), acc[2]);
    acc[3] = fmaf(m, fp8dec_sw(v.x >> 24), acc[3]);
    acc[4] = fmaf(m, fp8dec_sw(v.y & 0xffu), acc[4]);
    acc[5] = fmaf(m, fp8dec_sw((v.y >> 8) & 0xffu), acc[5]);
    acc[6] = fmaf(m, fp8dec_sw((v.y >> 16) & 0xffu), acc[6]);
    acc[7] = fmaf(m, fp8dec_sw(v.y >> 24), acc[7]);
#endif
}
// encode 4 floats -> packed fp8 word
__device__ __forceinline__ unsigned int enc4(float a0, float a1, float a2, float a3) {
#if HWFP8
    int o = 0;
    o = __builtin_amdgcn_cvt_pk_fp8_f32(a0, a1, o, false);
    o = __builtin_amdgcn_cvt_pk_fp8_f32(a2, a3, o, true);
    return (unsigned int)o;
#else
    return fp8enc_sw(a0) | (fp8enc_sw(a1) << 8) | (fp8enc_sw(a2) << 16) | (fp8enc_sw(a3) << 24);
#endif
}

// ---- prep: zero padded cnt (blocks 0..ZB-1) + pack W1,W2 (blocks ZB..ZB+15) ----
__global__ __launch_bounds__(256) void prep(uint4* __restrict__ cntz,
                                            const float* __restrict__ W1,
                                            const float* __restrict__ W2,
                                            unsigned short* __restrict__ Wp) {
    int b = blockIdx.x;
    if (b < ZB) {
        int i = b * 256 + threadIdx.x;          // cnt = NN*CSTR ints = NN*4 uint4
        if (i < NN * CSTR / 4) cntz[i] = make_uint4(0u, 0u, 0u, 0u);
        return;
    }
    int gid = (b - ZB) * 256 + threadIdx.x;     // [0, 4096)
    if (gid >= 4096) return;
    const float* W = (gid < 2048) ? W1 : W2;
    int g = gid & 2047;
    int f = g >> 6, l = g & 63;
    int ct = f >> 2, kb = f & 3;
    int col = ct * 16 + (l & 15);
    int k0 = kb * 32 + (l >> 4) * 8;
    unsigned short t[8];
#pragma unroll
    for (int i = 0; i < 8; ++i) t[i] = f2bf(W[(k0 + i) * CH + col]);
    uint4 v;
    v.x = (unsigned)t[0] | ((unsigned)t[1] << 16);
    v.y = (unsigned)t[2] | ((unsigned)t[3] << 16);
    v.z = (unsigned)t[4] | ((unsigned)t[5] << 16);
    v.w = (unsigned)t[6] | ((unsigned)t[7] << 16);
    ((uint4*)Wp)[gid] = v;
}

// ---- split grid, NO LDS: blocks [0,G1B) gemm1 (fp8 out); rest simple fill ----
// Fill is un-partitioned (partition filter refuted: no write-locality benefit,
// 8x thread + dstIdx-read overhead). Padded counters kept (+2-3us measured).
__global__ __launch_bounds__(256) void fillgemm1(const float* __restrict__ v0,
                                                 const unsigned short* __restrict__ Wp,
                                                 unsigned char* __restrict__ Hb,
                                                 const int* __restrict__ srcIdx,
                                                 const int* __restrict__ dstIdx,
                                                 int* __restrict__ cnt,
                                                 unsigned short* __restrict__ slots) {
    int b = blockIdx.x, tid = threadIdx.x;
    if (b >= G1B) {
        int e = (b - G1B) * 256 + tid;
        if (e < NE) {
            int d = dstIdx[e];
            int p = atomicAdd(&cnt[(size_t)d * CSTR], 1);
            if (p < CAP) slots[(size_t)d * CAP + p] = (unsigned short)srcIdx[e];
        }
        return;
    }
    // gemm1: rows b*64..+63, f32 input, W fragments from global (L2-resident)
    int w = tid >> 6, l = tid & 63;
    int row = b * 64 + w * 16 + (l & 15);
    int rc = min(row, NN - 1);
    int kq = l >> 4;

    bf16x8 xf[4];
#pragma unroll
    for (int kb = 0; kb < 4; ++kb) {
        const float* p = v0 + (size_t)rc * CH + kb * 32 + kq * 8;
        float4 a = *(const float4*)p;
        float4 bq = *(const float4*)(p + 4);
        union { bf16x8 v; unsigned int u[4]; } r;
        r.u[0] = (unsigned)f2bf(a.x) | ((unsigned)f2bf(a.y) << 16);
        r.u[1] = (unsigned)f2bf(a.z) | ((unsigned)f2bf(a.w) << 16);
        r.u[2] = (unsigned)f2bf(bq.x) | ((unsigned)f2bf(bq.y) << 16);
        r.u[3] = (unsigned)f2bf(bq.z) | ((unsigned)f2bf(bq.w) << 16);
        xf[kb] = r.v;
    }

    f32x4 acc[8];
#pragma unroll
    for (int ct = 0; ct < 8; ++ct) acc[ct] = (f32x4){0.f, 0.f, 0.f, 0.f};
#pragma unroll 2
    for (int ct = 0; ct < 8; ++ct)
#pragma unroll
        for (int kb = 0; kb < 4; ++kb) {
            bf16x8 wf = *(const bf16x8*)&Wp[((ct * 4 + kb) * 64 + l) * 8];
            acc[ct] = __builtin_amdgcn_mfma_f32_16x16x32_bf16(wf, xf[kb], acc[ct], 0, 0, 0);
        }

    if (row < NN) {
        unsigned char* yrow = Hb + (size_t)row * CH;
#pragma unroll
        for (int ct = 0; ct < 8; ++ct) {
            int col = ct * 16 + kq * 4;
            *(unsigned int*)(yrow + col) = enc4(acc[ct][0], acc[ct][1], acc[ct][2], acc[ct][3]);
        }
    }
}

// ---- lean gather: x = relu(agg(h1) + b1), fp8 in/out. 1 node per 16-lane group ----
__global__ __launch_bounds__(256) void gather_relu(const uint2* __restrict__ H64,
                                                   const int* __restrict__ cnt,
                                                   const unsigned short* __restrict__ slots,
                                                   const float* __restrict__ bias,
                                                   unsigned char* __restrict__ Xb1) {
    int tid = threadIdx.x;
    int g = tid >> 4, t = tid & 15;
    int node = blockIdx.x * 16 + g;
    if (node >= NN) return;
    int d = min(cnt[(size_t)node * CSTR], CAP);
    const unsigned short* sl = slots + (size_t)node * CAP;
    int last = d - 1;

    float acc[8];
#pragma unroll
    for (int k = 0; k < 8; ++k) acc[k] = 0.f;

    for (int i = 0; i < d; i += 8) {
        int e0 = sl[i];
        int e1 = sl[min(i + 1, last)];
        int e2 = sl[min(i + 2, last)];
        int e3 = sl[min(i + 3, last)];
        int e4 = sl[min(i + 4, last)];
        int e5 = sl[min(i + 5, last)];
        int e6 = sl[min(i + 6, last)];
        int e7 = sl[min(i + 7, last)];
        float m1 = (i + 1 <= last) ? 1.f : 0.f;
        float m2 = (i + 2 <= last) ? 1.f : 0.f;
        float m3 = (i + 3 <= last) ? 1.f : 0.f;
        float m4 = (i + 4 <= last) ? 1.f : 0.f;
        float m5 = (i + 5 <= last) ? 1.f : 0.f;
        float m6 = (i + 6 <= last) ? 1.f : 0.f;
        float m7 = (i + 7 <= last) ? 1.f : 0.f;
        uint2 v0 = H64[(size_t)e0 * 16 + t];
        uint2 v1 = H64[(size_t)e1 * 16 + t];
        uint2 v2 = H64[(size_t)e2 * 16 + t];
        uint2 v3 = H64[(size_t)e3 * 16 + t];
        uint2 v4 = H64[(size_t)e4 * 16 + t];
        uint2 v5 = H64[(size_t)e5 * 16 + t];
        uint2 v6 = H64[(size_t)e6 * 16 + t];
        uint2 v7 = H64[(size_t)e7 * 16 + t];
        acc_fp8(acc, v0, 1.f);
        acc_fp8(acc, v1, m1);
        acc_fp8(acc, v2, m2);
        acc_fp8(acc, v3, m3);
        acc_fp8(acc, v4, m4);
        acc_fp8(acc, v5, m5);
        acc_fp8(acc, v6, m6);
        acc_fp8(acc, v7, m7);
    }

    float4 bA = *(const float4*)&bias[t * 8];
    float4 bB = *(const float4*)&bias[t * 8 + 4];
    acc[0] += bA.x; acc[1] += bA.y; acc[2] += bA.z; acc[3] += bA.w;
    acc[4] += bB.x; acc[5] += bB.y; acc[6] += bB.z; acc[7] += bB.w;
#pragma unroll
    for (int k = 0; k < 8; ++k) acc[k] = fmaxf(acc[k], 0.f);

    uint2 o;
    o.x = enc4(acc[0], acc[1], acc[2], acc[3]);
    o.y = enc4(acc[4], acc[5], acc[6], acc[7]);
    ((uint2*)Xb1)[(size_t)node * 16 + t] = o;
}

// ---- fused layer 2: 128 threads / 32-row tile (2x grid for occupancy) ----
__global__ __launch_bounds__(128) void ggemm2(const uint4* __restrict__ H128,
                                              const int* __restrict__ cnt,
                                              const unsigned short* __restrict__ slots,
                                              const float* __restrict__ bias,
                                              const unsigned short* __restrict__ Wp,
                                              float* __restrict__ Yf32) {
    __shared__ unsigned short Xl[32 * XPAD];     // 8.5 KiB agg-tile
    int tid = threadIdx.x;
    int g = tid >> 3, t = tid & 7;
    int base = blockIdx.x * 32;

    for (int j = 0; j < 2; ++j) {
        int nl = g * 2 + j;
        int node = base + nl;
        float acc[16];
#pragma unroll
        for (int k = 0; k < 16; ++k) acc[k] = 0.f;
        if (node < NN) {
            int d = min(cnt[(size_t)node * CSTR], CAP);
            const unsigned short* sl = slots + (size_t)node * CAP;
            int last = d - 1;
            for (int i = 0; i < d; i += 8) {
                int e0 = sl[i];
                int e1 = sl[min(i + 1, last)];
                int e2 = sl[min(i + 2, last)];
                int e3 = sl[min(i + 3, last)];
                int e4 = sl[min(i + 4, last)];
                int e5 = sl[min(i + 5, last)];
                int e6 = sl[min(i + 6, last)];
                int e7 = sl[min(i + 7, last)];
                float m1 = (i + 1 <= last) ? 1.f : 0.f;
                float m2 = (i + 2 <= last) ? 1.f : 0.f;
                float m3 = (i + 3 <= last) ? 1.f : 0.f;
                float m4 = (i + 4 <= last) ? 1.f : 0.f;
                float m5 = (i + 5 <= last) ? 1.f : 0.f;
                float m6 = (i + 6 <= last) ? 1.f : 0.f;
                float m7 = (i + 7 <= last) ? 1.f : 0.f;
                uint4 v0 = H128[(size_t)e0 * 8 + t];
                uint4 v1 = H128[(size_t)e1 * 8 + t];
                uint4 v2 = H128[(size_t)e2 * 8 + t];
                uint4 v3 = H128[(size_t)e3 * 8 + t];
                uint4 v4 = H128[(size_t)e4 * 8 + t];
                uint4 v5 = H128[(size_t)e5 * 8 + t];
                uint4 v6 = H128[(size_t)e6 * 8 + t];
                uint4 v7 = H128[(size_t)e7 * 8 + t];
                acc_fp8(acc, make_uint2(v0.x, v0.y), 1.f);
                acc_fp8(acc + 8, make_uint2(v0.z, v0.w), 1.f);
                acc_fp8(acc, make_uint2(v1.x, v1.y), m1);
                acc_fp8(acc + 8, make_uint2(v1.z, v1.w), m1);
                acc_fp8(acc, make_uint2(v2.x, v2.y), m2);
                acc_fp8(acc + 8, make_uint2(v2.z, v2.w), m2);
                acc_fp8(acc, make_uint2(v3.x, v3.y), m3);
                acc_fp8(acc + 8, make_uint2(v3.z, v3.w), m3);
                acc_fp8(acc, make_uint2(v4.x, v4.y), m4);
                acc_fp8(acc + 8, make_uint2(v4.z, v4.w), m4);
                acc_fp8(acc, make_uint2(v5.x, v5.y), m5);
                acc_fp8(acc + 8, make_uint2(v5.z, v5.w), m5);
                acc_fp8(acc, make_uint2(v6.x, v6.y), m6);
                acc_fp8(acc + 8, make_uint2(v6.z, v6.w), m6);
                acc_fp8(acc, make_uint2(v7.x, v7.y), m7);
                acc_fp8(acc + 8, make_uint2(v7.z, v7.w), m7);
            }
        }
        uint4 o0, o1;
        o0.x = (unsigned)f2bf(acc[0]) | ((unsigned)f2bf(acc[1]) << 16);
        o0.y = (unsigned)f2bf(acc[2]) | ((unsigned)f2bf(acc[3]) << 16);
        o0.z = (unsigned)f2bf(acc[4]) | ((unsigned)f2bf(acc[5]) << 16);
        o0.w = (unsigned)f2bf(acc[6]) | ((unsigned)f2bf(acc[7]) << 16);
        o1.x = (unsigned)f2bf(acc[8]) | ((unsigned)f2bf(acc[9]) << 16);
        o1.y = (unsigned)f2bf(acc[10]) | ((unsigned)f2bf(acc[11]) << 16);
        o1.z = (unsigned)f2bf(acc[12]) | ((unsigned)f2bf(acc[13]) << 16);
        o1.w = (unsigned)f2bf(acc[14]) | ((unsigned)f2bf(acc[15]) << 16);
        *(uint4*)&Xl[nl * XPAD + t * 16] = o0;
        *(uint4*)&Xl[nl * XPAD + t * 16 + 8] = o1;
    }
    __syncthreads();

    // Phase B: out = aggX @ W2 + b2 (f32 from accumulator); W from global (L2)
    int w = tid >> 6, l = tid & 63;
    int rowl = w * 16 + (l & 15);
    int kq = l >> 4;
    bf16x8 xf[4];
#pragma unroll
    for (int kb = 0; kb < 4; ++kb)
        xf[kb] = *(const bf16x8*)&Xl[rowl * XPAD + kb * 32 + kq * 8];

    f32x4 acq[8];
#pragma unroll
    for (int ct = 0; ct < 8; ++ct) acq[ct] = (f32x4){0.f, 0.f, 0.f, 0.f};
#pragma unroll 2
    for (int ct = 0; ct < 8; ++ct)
#pragma unroll
        for (int kb = 0; kb < 4; ++kb) {
            bf16x8 wf = *(const bf16x8*)&Wp[((ct * 4 + kb) * 64 + l) * 8];
            acq[ct] = __builtin_amdgcn_mfma_f32_16x16x32_bf16(wf, xf[kb], acq[ct], 0, 0, 0);
        }

    int row = base + rowl;
    if (row < NN) {
#pragma unroll
        for (int ct = 0; ct < 8; ++ct) {
            int col = ct * 16 + kq * 4;
            float4 bv = *(const float4*)&bias[col];
            *(float4*)&Yf32[(size_t)row * CH + col] =
                make_float4(acq[ct][0] + bv.x, acq[ct][1] + bv.y,
                            acq[ct][2] + bv.z, acq[ct][3] + bv.w);
        }
    }
}

extern "C" void kernel_launch(void* const* d_in, const int* in_sizes, int n_in,
                              void* d_out, int out_size, void* d_ws, size_t ws_size,
                              hipStream_t stream) {
    const float* v0 = (const float*)d_in[0];
    const int* edge = (const int*)d_in[1];   // [2, NE]: row0 = src, row1 = dst
    const float* W1 = (const float*)d_in[2];
    const float* b1 = (const float*)d_in[3];
    const float* W2 = (const float*)d_in[4];
    const float* b2 = (const float*)d_in[5];
    float* out = (float*)d_out;

    const int* srcIdx = edge;
    const int* dstIdx = edge + NE;

    // workspace layout
    unsigned char* Hb     = (unsigned char*)d_ws;        // [NN*CH] fp8 h1
    unsigned char* Xb1    = Hb + (size_t)NN * CH;        // [NN*CH] fp8 x
    unsigned short* Wp    = (unsigned short*)(Xb1 + (size_t)NN * CH); // [2*16384] packed W
    int* cnt              = (int*)(Wp + 2 * 16384);      // [NN*CSTR] padded counters
    unsigned short* slots = (unsigned short*)(cnt + (size_t)NN * CSTR); // [NN*CAP]

    // K0: zero padded counters + pack weights
    prep<<<ZB + 16, 256, 0, stream>>>((uint4*)cnt, W1, W2, Wp);

    // K1: gemm1 h1=v0@W1 (blocks 0..781) || simple edge fill (rest)
    fillgemm1<<<G1B + FILLB, 256, 0, stream>>>(v0, Wp, Hb, srcIdx, dstIdx, cnt, slots);

    // K2: x = relu(agg(h1) + b1) -> fp8
    gather_relu<<<(NN + 15) / 16, 256, 0, stream>>>((const uint2*)Hb, cnt, slots, b1, Xb1);

    // K3: out = (agg x) @ W2 + b2  (32-row tiles, 2x grid)
    ggemm2<<<(NN + 31) / 32, 128, 0, stream>>>((const uint4*)Xb1, cnt, slots, b2,
                                               Wp + 16384, out);
}

// Round 23
// 86.465 us; speedup vs baseline: 1.1914x; 1.1914x over previous
//
#include <hip/hip_runtime.h>

#define NN 50000
#define NE 640000
#define CH 128
#define CAP 64                          // slots per node; P(deg>=64)~e^-61 for Poisson(12.8)
#define G1B ((NN + 63) / 64)            // 782 gemm1 blocks
#define FILLB ((NE + 255) / 256)        // 2500 edge chunks
#define NPART 8
#define PSZ (NN / NPART)
#define XPAD 136                        // LDS x-tile pitch (ushorts)
#define CSTR 16                         // cnt stride in ints: 1 counter per 64B line
#define ZB ((NN * CSTR / 4 + 255) / 256)  // zero blocks (uint4)

typedef __attribute__((ext_vector_type(8))) short bf16x8;
typedef __attribute__((ext_vector_type(4))) float f32x4;
typedef __attribute__((ext_vector_type(2))) float f32x2;

#if __has_builtin(__builtin_amdgcn_cvt_pk_f32_fp8) && __has_builtin(__builtin_amdgcn_cvt_pk_fp8_f32)
#define HWFP8 1
#else
#define HWFP8 0
#endif

// f32 -> bf16 (RNE)
__device__ __forceinline__ unsigned short f2bf(float x) {
    unsigned int b = __float_as_uint(x);
    b += 0x7fffu + ((b >> 16) & 1u);
    return (unsigned short)(b >> 16);
}

// ---- fp8 e4m3 manual fallback codecs ----
__device__ __forceinline__ float fp8dec_sw(unsigned int b) {
    unsigned int m = (b & 0x7fu) << 20;
    unsigned int v = m ? (m + 0x3C000000u) : 0u;
    v |= (b & 0x80u) << 24;
    return __uint_as_float(v);
}
__device__ __forceinline__ unsigned int fp8enc_sw(float x) {
    unsigned int u = __float_as_uint(x);
    unsigned int s = (u >> 24) & 0x80u;
    u &= 0x7fffffffu;
    if (u > 0x43E00000u) u = 0x43E00000u;
    unsigned int r = u + 0x7FFFFu + ((u >> 20) & 1u);
    int b = (int)(r >> 20) - 960;
    b = b < 0 ? 0 : (b > 126 ? 126 : b);
    return s | (unsigned int)b;
}

// accumulate one fp8 row-chunk (8 channels in uint2) with mask m
__device__ __forceinline__ void acc_fp8(float* acc, uint2 v, float m) {
#if HWFP8
    f32x2 p0 = __builtin_amdgcn_cvt_pk_f32_fp8((int)v.x, false);
    f32x2 p1 = __builtin_amdgcn_cvt_pk_f32_fp8((int)v.x, true);
    f32x2 p2 = __builtin_amdgcn_cvt_pk_f32_fp8((int)v.y, false);
    f32x2 p3 = __builtin_amdgcn_cvt_pk_f32_fp8((int)v.y, true);
    acc[0] = fmaf(m, p0[0], acc[0]); acc[1] = fmaf(m, p0[1], acc[1]);
    acc[2] = fmaf(m, p1[0], acc[2]); acc[3] = fmaf(m, p1[1], acc[3]);
    acc[4] = fmaf(m, p2[0], acc[4]); acc[5] = fmaf(m, p2[1], acc[5]);
    acc[6] = fmaf(m, p3[0], acc[6]); acc[7] = fmaf(m, p3[1], acc[7]);
#else
    acc[0] = fmaf(m, fp8dec_sw(v.x & 0xffu), acc[0]);
    acc[1] = fmaf(m, fp8dec_sw((v.x >> 8) & 0xffu), acc[1]);
    acc[2] = fmaf(m, fp8dec_sw((v.x >> 16) & 0xffu), acc[2]);
    acc[3] = fmaf(m, fp8dec_sw(v.x >> 24), acc[3]);
    acc[4] = fmaf(m, fp8dec_sw(v.y & 0xffu), acc[4]);
    acc[5] = fmaf(m, fp8dec_sw((v.y >> 8) & 0xffu), acc[5]);
    acc[6] = fmaf(m, fp8dec_sw((v.y >> 16) & 0xffu), acc[6]);
    acc[7] = fmaf(m, fp8dec_sw(v.y >> 24), acc[7]);
#endif
}
// encode 4 floats -> packed fp8 word
__device__ __forceinline__ unsigned int enc4(float a0, float a1, float a2, float a3) {
#if HWFP8
    int o = 0;
    o = __builtin_amdgcn_cvt_pk_fp8_f32(a0, a1, o, false);
    o = __builtin_amdgcn_cvt_pk_fp8_f32(a2, a3, o, true);
    return (unsigned int)o;
#else
    return fp8enc_sw(a0) | (fp8enc_sw(a1) << 8) | (fp8enc_sw(a2) << 16) | (fp8enc_sw(a3) << 24);
#endif
}

// ---- prep: zero padded cnt (blocks 0..ZB-1) + pack W1,W2 (blocks ZB..ZB+15) ----
__global__ __launch_bounds__(256) void prep(uint4* __restrict__ cntz,
                                            const float* __restrict__ W1,
                                            const float* __restrict__ W2,
                                            unsigned short* __restrict__ Wp) {
    int b = blockIdx.x;
    if (b < ZB) {
        int i = b * 256 + threadIdx.x;          // cnt = NN*CSTR ints = NN*4 uint4
        if (i < NN * CSTR / 4) cntz[i] = make_uint4(0u, 0u, 0u, 0u);
        return;
    }
    int gid = (b - ZB) * 256 + threadIdx.x;     // [0, 4096)
    if (gid >= 4096) return;
    const float* W = (gid < 2048) ? W1 : W2;
    int g = gid & 2047;
    int f = g >> 6, l = g & 63;
    int ct = f >> 2, kb = f & 3;
    int col = ct * 16 + (l & 15);
    int k0 = kb * 32 + (l >> 4) * 8;
    unsigned short t[8];
#pragma unroll
    for (int i = 0; i < 8; ++i) t[i] = f2bf(W[(k0 + i) * CH + col]);
    uint4 v;
    v.x = (unsigned)t[0] | ((unsigned)t[1] << 16);
    v.y = (unsigned)t[2] | ((unsigned)t[3] << 16);
    v.z = (unsigned)t[4] | ((unsigned)t[5] << 16);
    v.w = (unsigned)t[6] | ((unsigned)t[7] << 16);
    ((uint4*)Wp)[gid] = v;
}

// ---- split grid, NO LDS: blocks [0,G1B) gemm1 (fp8 out); rest partitioned fill ----
// Partition filter (dst in 1/8 range per block) confines each wave's slot-write
// working set to 800KB -> L2 temporal locality -> WRITE_SIZE 41.6->30MB (R22
// control experiment proved this; mechanism is working-set, not XCD affinity).
__global__ __launch_bounds__(256) void fillgemm1(const float* __restrict__ v0,
                                                 const unsigned short* __restrict__ Wp,
                                                 unsigned char* __restrict__ Hb,
                                                 const int* __restrict__ srcIdx,
                                                 const int* __restrict__ dstIdx,
                                                 int* __restrict__ cnt,
                                                 unsigned short* __restrict__ slots) {
    int b = blockIdx.x, tid = threadIdx.x;
    if (b >= G1B) {
        int f = b - G1B;
        int part = b & (NPART - 1);
        int e = (f >> 3) * 256 + tid;
        if (e >= NE) return;
        int d = dstIdx[e];
        int lo = part * PSZ;
        if (d < lo || d >= lo + PSZ) return;
        int p = atomicAdd(&cnt[(size_t)d * CSTR], 1);
        if (p < CAP) slots[(size_t)d * CAP + p] = (unsigned short)srcIdx[e];
        return;
    }
    // gemm1: rows b*64..+63, f32 input, W fragments from global (L2-resident)
    int w = tid >> 6, l = tid & 63;
    int row = b * 64 + w * 16 + (l & 15);
    int rc = min(row, NN - 1);
    int kq = l >> 4;

    bf16x8 xf[4];
#pragma unroll
    for (int kb = 0; kb < 4; ++kb) {
        const float* p = v0 + (size_t)rc * CH + kb * 32 + kq * 8;
        float4 a = *(const float4*)p;
        float4 bq = *(const float4*)(p + 4);
        union { bf16x8 v; unsigned int u[4]; } r;
        r.u[0] = (unsigned)f2bf(a.x) | ((unsigned)f2bf(a.y) << 16);
        r.u[1] = (unsigned)f2bf(a.z) | ((unsigned)f2bf(a.w) << 16);
        r.u[2] = (unsigned)f2bf(bq.x) | ((unsigned)f2bf(bq.y) << 16);
        r.u[3] = (unsigned)f2bf(bq.z) | ((unsigned)f2bf(bq.w) << 16);
        xf[kb] = r.v;
    }

    f32x4 acc[8];
#pragma unroll
    for (int ct = 0; ct < 8; ++ct) acc[ct] = (f32x4){0.f, 0.f, 0.f, 0.f};
#pragma unroll 2
    for (int ct = 0; ct < 8; ++ct)
#pragma unroll
        for (int kb = 0; kb < 4; ++kb) {
            bf16x8 wf = *(const bf16x8*)&Wp[((ct * 4 + kb) * 64 + l) * 8];
            acc[ct] = __builtin_amdgcn_mfma_f32_16x16x32_bf16(wf, xf[kb], acc[ct], 0, 0, 0);
        }

    if (row < NN) {
        unsigned char* yrow = Hb + (size_t)row * CH;
#pragma unroll
        for (int ct = 0; ct < 8; ++ct) {
            int col = ct * 16 + kq * 4;
            *(unsigned int*)(yrow + col) = enc4(acc[ct][0], acc[ct][1], acc[ct][2], acc[ct][3]);
        }
    }
}

// ---- lean gather: x = relu(agg(h1) + b1), fp8 in/out. 1 node per 16-lane group ----
__global__ __launch_bounds__(256) void gather_relu(const uint2* __restrict__ H64,
                                                   const int* __restrict__ cnt,
                                                   const unsigned short* __restrict__ slots,
                                                   const float* __restrict__ bias,
                                                   unsigned char* __restrict__ Xb1) {
    int tid = threadIdx.x;
    int g = tid >> 4, t = tid & 15;
    int node = blockIdx.x * 16 + g;
    if (node >= NN) return;
    int d = min(cnt[(size_t)node * CSTR], CAP);
    const unsigned short* sl = slots + (size_t)node * CAP;
    int last = d - 1;

    float acc[8];
#pragma unroll
    for (int k = 0; k < 8; ++k) acc[k] = 0.f;

    for (int i = 0; i < d; i += 8) {
        int e0 = sl[i];
        int e1 = sl[min(i + 1, last)];
        int e2 = sl[min(i + 2, last)];
        int e3 = sl[min(i + 3, last)];
        int e4 = sl[min(i + 4, last)];
        int e5 = sl[min(i + 5, last)];
        int e6 = sl[min(i + 6, last)];
        int e7 = sl[min(i + 7, last)];
        float m1 = (i + 1 <= last) ? 1.f : 0.f;
        float m2 = (i + 2 <= last) ? 1.f : 0.f;
        float m3 = (i + 3 <= last) ? 1.f : 0.f;
        float m4 = (i + 4 <= last) ? 1.f : 0.f;
        float m5 = (i + 5 <= last) ? 1.f : 0.f;
        float m6 = (i + 6 <= last) ? 1.f : 0.f;
        float m7 = (i + 7 <= last) ? 1.f : 0.f;
        uint2 v0 = H64[(size_t)e0 * 16 + t];
        uint2 v1 = H64[(size_t)e1 * 16 + t];
        uint2 v2 = H64[(size_t)e2 * 16 + t];
        uint2 v3 = H64[(size_t)e3 * 16 + t];
        uint2 v4 = H64[(size_t)e4 * 16 + t];
        uint2 v5 = H64[(size_t)e5 * 16 + t];
        uint2 v6 = H64[(size_t)e6 * 16 + t];
        uint2 v7 = H64[(size_t)e7 * 16 + t];
        acc_fp8(acc, v0, 1.f);
        acc_fp8(acc, v1, m1);
        acc_fp8(acc, v2, m2);
        acc_fp8(acc, v3, m3);
        acc_fp8(acc, v4, m4);
        acc_fp8(acc, v5, m5);
        acc_fp8(acc, v6, m6);
        acc_fp8(acc, v7, m7);
    }

    float4 bA = *(const float4*)&bias[t * 8];
    float4 bB = *(const float4*)&bias[t * 8 + 4];
    acc[0] += bA.x; acc[1] += bA.y; acc[2] += bA.z; acc[3] += bA.w;
    acc[4] += bB.x; acc[5] += bB.y; acc[6] += bB.z; acc[7] += bB.w;
#pragma unroll
    for (int k = 0; k < 8; ++k) acc[k] = fmaxf(acc[k], 0.f);

    uint2 o;
    o.x = enc4(acc[0], acc[1], acc[2], acc[3]);
    o.y = enc4(acc[4], acc[5], acc[6], acc[7]);
    ((uint2*)Xb1)[(size_t)node * 16 + t] = o;
}

// ---- fused layer 2: 128 threads / 32-row tile (2x grid for occupancy) ----
__global__ __launch_bounds__(128) void ggemm2(const uint4* __restrict__ H128,
                                              const int* __restrict__ cnt,
                                              const unsigned short* __restrict__ slots,
                                              const float* __restrict__ bias,
                                              const unsigned short* __restrict__ Wp,
                                              float* __restrict__ Yf32) {
    __shared__ unsigned short Xl[32 * XPAD];     // 8.5 KiB agg-tile
    int tid = threadIdx.x;
    int g = tid >> 3, t = tid & 7;
    int base = blockIdx.x * 32;

    for (int j = 0; j < 2; ++j) {
        int nl = g * 2 + j;
        int node = base + nl;
        float acc[16];
#pragma unroll
        for (int k = 0; k < 16; ++k) acc[k] = 0.f;
        if (node < NN) {
            int d = min(cnt[(size_t)node * CSTR], CAP);
            const unsigned short* sl = slots + (size_t)node * CAP;
            int last = d - 1;
            for (int i = 0; i < d; i += 8) {
                int e0 = sl[i];
                int e1 = sl[min(i + 1, last)];
                int e2 = sl[min(i + 2, last)];
                int e3 = sl[min(i + 3, last)];
                int e4 = sl[min(i + 4, last)];
                int e5 = sl[min(i + 5, last)];
                int e6 = sl[min(i + 6, last)];
                int e7 = sl[min(i + 7, last)];
                float m1 = (i + 1 <= last) ? 1.f : 0.f;
                float m2 = (i + 2 <= last) ? 1.f : 0.f;
                float m3 = (i + 3 <= last) ? 1.f : 0.f;
                float m4 = (i + 4 <= last) ? 1.f : 0.f;
                float m5 = (i + 5 <= last) ? 1.f : 0.f;
                float m6 = (i + 6 <= last) ? 1.f : 0.f;
                float m7 = (i + 7 <= last) ? 1.f : 0.f;
                uint4 v0 = H128[(size_t)e0 * 8 + t];
                uint4 v1 = H128[(size_t)e1 * 8 + t];
                uint4 v2 = H128[(size_t)e2 * 8 + t];
                uint4 v3 = H128[(size_t)e3 * 8 + t];
                uint4 v4 = H128[(size_t)e4 * 8 + t];
                uint4 v5 = H128[(size_t)e5 * 8 + t];
                uint4 v6 = H128[(size_t)e6 * 8 + t];
                uint4 v7 = H128[(size_t)e7 * 8 + t];
                acc_fp8(acc, make_uint2(v0.x, v0.y), 1.f);
                acc_fp8(acc + 8, make_uint2(v0.z, v0.w), 1.f);
                acc_fp8(acc, make_uint2(v1.x, v1.y), m1);
                acc_fp8(acc + 8, make_uint2(v1.z, v1.w), m1);
                acc_fp8(acc, make_uint2(v2.x, v2.y), m2);
                acc_fp8(acc + 8, make_uint2(v2.z, v2.w), m2);
                acc_fp8(acc, make_uint2(v3.x, v3.y), m3);
                acc_fp8(acc + 8, make_uint2(v3.z, v3.w), m3);
                acc_fp8(acc, make_uint2(v4.x, v4.y), m4);
                acc_fp8(acc + 8, make_uint2(v4.z, v4.w), m4);
                acc_fp8(acc, make_uint2(v5.x, v5.y), m5);
                acc_fp8(acc + 8, make_uint2(v5.z, v5.w), m5);
                acc_fp8(acc, make_uint2(v6.x, v6.y), m6);
                acc_fp8(acc + 8, make_uint2(v6.z, v6.w), m6);
                acc_fp8(acc, make_uint2(v7.x, v7.y), m7);
                acc_fp8(acc + 8, make_uint2(v7.z, v7.w), m7);
            }
        }
        uint4 o0, o1;
        o0.x = (unsigned)f2bf(acc[0]) | ((unsigned)f2bf(acc[1]) << 16);
        o0.y = (unsigned)f2bf(acc[2]) | ((unsigned)f2bf(acc[3]) << 16);
        o0.z = (unsigned)f2bf(acc[4]) | ((unsigned)f2bf(acc[5]) << 16);
        o0.w = (unsigned)f2bf(acc[6]) | ((unsigned)f2bf(acc[7]) << 16);
        o1.x = (unsigned)f2bf(acc[8]) | ((unsigned)f2bf(acc[9]) << 16);
        o1.y = (unsigned)f2bf(acc[10]) | ((unsigned)f2bf(acc[11]) << 16);
        o1.z = (unsigned)f2bf(acc[12]) | ((unsigned)f2bf(acc[13]) << 16);
        o1.w = (unsigned)f2bf(acc[14]) | ((unsigned)f2bf(acc[15]) << 16);
        *(uint4*)&Xl[nl * XPAD + t * 16] = o0;
        *(uint4*)&Xl[nl * XPAD + t * 16 + 8] = o1;
    }
    __syncthreads();

    // Phase B: out = aggX @ W2 + b2 (f32 from accumulator); W from global (L2)
    int w = tid >> 6, l = tid & 63;
    int rowl = w * 16 + (l & 15);
    int kq = l >> 4;
    bf16x8 xf[4];
#pragma unroll
    for (int kb = 0; kb < 4; ++kb)
        xf[kb] = *(const bf16x8*)&Xl[rowl * XPAD + kb * 32 + kq * 8];

    f32x4 acq[8];
#pragma unroll
    for (int ct = 0; ct < 8; ++ct) acq[ct] = (f32x4){0.f, 0.f, 0.f, 0.f};
#pragma unroll 2
    for (int ct = 0; ct < 8; ++ct)
#pragma unroll
        for (int kb = 0; kb < 4; ++kb) {
            bf16x8 wf = *(const bf16x8*)&Wp[((ct * 4 + kb) * 64 + l) * 8];
            acq[ct] = __builtin_amdgcn_mfma_f32_16x16x32_bf16(wf, xf[kb], acq[ct], 0, 0, 0);
        }

    int row = base + rowl;
    if (row < NN) {
#pragma unroll
        for (int ct = 0; ct < 8; ++ct) {
            int col = ct * 16 + kq * 4;
            float4 bv = *(const float4*)&bias[col];
            *(float4*)&Yf32[(size_t)row * CH + col] =
                make_float4(acq[ct][0] + bv.x, acq[ct][1] + bv.y,
                            acq[ct][2] + bv.z, acq[ct][3] + bv.w);
        }
    }
}

extern "C" void kernel_launch(void* const* d_in, const int* in_sizes, int n_in,
                              void* d_out, int out_size, void* d_ws, size_t ws_size,
                              hipStream_t stream) {
    const float* v0 = (const float*)d_in[0];
    const int* edge = (const int*)d_in[1];   // [2, NE]: row0 = src, row1 = dst
    const float* W1 = (const float*)d_in[2];
    const float* b1 = (const float*)d_in[3];
    const float* W2 = (const float*)d_in[4];
    const float* b2 = (const float*)d_in[5];
    float* out = (float*)d_out;

    const int* srcIdx = edge;
    const int* dstIdx = edge + NE;

    // workspace layout
    unsigned char* Hb     = (unsigned char*)d_ws;        // [NN*CH] fp8 h1
    unsigned char* Xb1    = Hb + (size_t)NN * CH;        // [NN*CH] fp8 x
    unsigned short* Wp    = (unsigned short*)(Xb1 + (size_t)NN * CH); // [2*16384] packed W
    int* cnt              = (int*)(Wp + 2 * 16384);      // [NN*CSTR] padded counters
    unsigned short* slots = (unsigned short*)(cnt + (size_t)NN * CSTR); // [NN*CAP]

    // K0: zero padded counters + pack weights
    prep<<<ZB + 16, 256, 0, stream>>>((uint4*)cnt, W1, W2, Wp);

    // K1: gemm1 h1=v0@W1 (blocks 0..781) || partitioned edge fill (rest)
    fillgemm1<<<G1B + FILLB * NPART, 256, 0, stream>>>(v0, Wp, Hb,
                                                       srcIdx, dstIdx, cnt, slots);

    // K2: x = relu(agg(h1) + b1) -> fp8
    gather_relu<<<(NN + 15) / 16, 256, 0, stream>>>((const uint2*)Hb, cnt, slots, b1, Xb1);

    // K3: out = (agg x) @ W2 + b2  (32-row tiles, 2x grid)
    ggemm2<<<(NN + 31) / 32, 128, 0, stream>>>((const uint4*)Xb1, cnt, slots, b2,
                                               Wp + 16384, out);
}